// Round 5
// baseline (1348.624 us; speedup 1.0000x reference)
//
#include <hip/hip_runtime.h>
#include <math.h>

#define BB 16
#define TT 500
#define CC 2048
#define SN 64
#define SD 512
#define NDEN 128        // 16 batches * 8 column-blocks
#define NTHR 512
#define SHIFTC 30.0f

// ws layout:
//   bytes [0, 1048576): u64 part[2][16][8][8][64]
//     tagged partial rows: [buf][batch][producerWG cb][producer wave wv][col]
//   float index 262144+: DACC[16], DSCALE[16], NACC[16], NSCALE[16]
#define PBUFO ((size_t)(16 * 8 * 8 * 64))   // u64s per buffer = 8192
#define WSF_DACC   262144
#define WSF_DSCALE 262160
#define WSF_NACC   262176
#define WSF_NSCALE 262192

#define AL(p) __hip_atomic_load((p), __ATOMIC_RELAXED, __HIP_MEMORY_SCOPE_AGENT)
#define AS(p, v) __hip_atomic_store((p), (v), __ATOMIC_RELAXED, __HIP_MEMORY_SCOPE_AGENT)

__device__ __forceinline__ float wave_max(float v) {
  #pragma unroll
  for (int off = 32; off > 0; off >>= 1) v = fmaxf(v, __shfl_xor(v, off, 64));
  return v;
}
__device__ __forceinline__ float wave_sum(float v) {
  #pragma unroll
  for (int off = 32; off > 0; off >>= 1) v += __shfl_xor(v, off, 64);
  return v;
}
__device__ __forceinline__ unsigned long long pk(unsigned tag, float v) {
  return ((unsigned long long)tag << 32) | (unsigned long long)__float_as_uint(v);
}
__device__ __forceinline__ float clamp30(float v) {
  return fminf(fmaxf(v, -30.f), 30.f);
}

__global__ __launch_bounds__(NTHR, 1) void fsm_fwd(
    const float* __restrict__ x, const int* __restrict__ seqlens,
    const float* __restrict__ nA, const float* __restrict__ nls,
    const float* __restrict__ nlf, const int* __restrict__ npdf,
    const float* __restrict__ dA, const float* __restrict__ dls,
    const float* __restrict__ dlf, const int* __restrict__ dpdf,
    unsigned long long* __restrict__ p64, float* __restrict__ wsf)
{
  __shared__ float pmx[2][8];   // double-buffered per-wave window maxes
  __shared__ float red[8];      // final reduction scratch
  const int tid = threadIdx.x;
  const int lane = tid & 63, wv = tid >> 6;

  if (blockIdx.x < NDEN) {
    // -------- DEN (shared A, S=512): partial-push, consumer-side assembly ----
    const int g  = blockIdx.x & 15;     // batch
    const int cb = blockIdx.x >> 4;     // column block (0..7)
    const int j0 = cb * 64;             // columns this WG produces partials for
    const int i0 = wv * 64;             // i-window this wave owns (and assembles)
    const int si = i0 + lane;           // the state this lane assembles

    // A in registers: lane holds exp(A[i0+k][j0+lane]), k=0..63
    float Areg[64];
    {
      const float* Ap = dA + (size_t)i0 * SD + j0 + lane;
      #pragma unroll
      for (int k = 0; k < 64; ++k)
        Areg[k] = __expf(Ap[(size_t)k * SD]);
    }

    const int   pdfj = dpdf[si];
    const float lfj  = dlf[si];
    const int   sl   = seqlens[g];
    const float* xb  = x + (size_t)g * TT * CC;

    // p_0 window computed locally (no exchange); redundant across the 8 WGs
    float pwin  = __expf(dls[si] + clamp30(xb[pdfj]) - SHIFTC);
    float scale = SHIFTC;
    {
      float wm = wave_max(pwin);
      if (lane == 0) pmx[0][wv] = wm;
    }
    __syncthreads();
    float lm;
    {
      float m = pmx[0][0];
      #pragma unroll
      for (int r = 1; r < 8; ++r) m = fmaxf(m, pmx[0][r]);
      lm = __logf(m);
    }

    unsigned long long* myrow = p64 + (((size_t)g * 8 + cb) * 8 + wv) * 64;
    unsigned long long* prows = p64 + (((size_t)g * 8 + wv) * 8) * 64;  // producer WG (g,wv)

    for (int t = 1; t < TT; ++t) {
      const size_t bo = (t & 1) ? PBUFO : 0;
      // prefetch emission for the state this lane assembles (hides under matvec+poll)
      float xq = clamp30(xb[(size_t)t * CC + pdfj]);

      // matvec partial for own columns from own p-window (pure VALU)
      float q = 0.f;
      #pragma unroll
      for (int k = 0; k < 64; ++k) {
        float pv = __uint_as_float(__builtin_amdgcn_readlane(__float_as_uint(pwin), k));
        q = fmaf(pv, Areg[k], q);
      }
      // publish raw partial row IMMEDIATELY — no barrier, no reduction first
      AS(myrow + bo + lane, pk((unsigned)t, q));

      // poll the 8 partial rows covering own i-window (producer WG (g,wv)),
      // re-reading only rows not yet tagged
      unsigned long long wr[8];
      const unsigned tg = (unsigned)t;
      unsigned long long* pr = prows + bo + lane;
      unsigned miss = 0xFFu;
      do {
        #pragma unroll
        for (int r = 0; r < 8; ++r)
          if (miss & (1u << r)) wr[r] = AL(pr + r * 64);
        #pragma unroll
        for (int r = 0; r < 8; ++r)
          if ((miss & (1u << r)) && (unsigned)(wr[r] >> 32) == tg) miss &= ~(1u << r);
      } while (miss);

      // assemble p_t for own state: fixed-order sum (bit-identical across WGs)
      float s = 0.f;
      #pragma unroll
      for (int r = 0; r < 8; ++r) s += __uint_as_float((unsigned)wr[r]);
      if (t < sl) {
        pwin = s * __expf(xq - SHIFTC - lm);
        scale += SHIFTC + lm;
      }
      // local (redundant) per-batch max for the lagged renormalizer; the barrier
      // here is off the global critical path (overlaps other WGs' polls)
      float wm = wave_max(pwin);
      if (lane == 0) pmx[t & 1][wv] = wm;
      __syncthreads();
      {
        float m = pmx[t & 1][0];
        #pragma unroll
        for (int r = 1; r < 8; ++r) m = fmaxf(m, pmx[t & 1][r]);
        lm = __logf(m);
      }
    }

    // final: every WG holds the full p_499; only cb==0 writes
    float part = wave_sum(pwin * __expf(lfj));
    if (lane == 0) red[wv] = part;
    __syncthreads();
    if (cb == 0 && tid == 0) {
      float sum = 0.f;
      #pragma unroll
      for (int r = 0; r < 8; ++r) sum += red[r];
      wsf[WSF_DACC + g]   = sum;
      wsf[WSF_DSCALE + g] = scale;
    }
  } else {
    // -------- NUM (per-batch A, S=64), single wave, pure VALU ---------------
    const int b = blockIdx.x - NDEN;
    if (wv != 0) return;

    float Areg[64];   // lane holds exp(nA[i][lane]) for all i
    {
      const float* Ap = nA + b * SN * SN + lane;
      #pragma unroll
      for (int i = 0; i < 64; ++i)
        Areg[i] = __expf(Ap[i * SN]);
    }
    const int   pdfj = npdf[b * SN + lane];
    const float lfj  = nlf[b * SN + lane];
    const int   sl   = seqlens[b];
    float xv = clamp30(x[(size_t)b * TT * CC + pdfj]);
    float pcur = __expf(nls[b * SN + lane] + xv - SHIFTC);
    float scale = SHIFTC;

    for (int t = 1; t < TT; ++t) {
      xv = clamp30(x[(size_t)b * TT * CC + t * CC + pdfj]);
      float pold = pcur;
      float q = 0.f;
      #pragma unroll
      for (int i = 0; i < 64; ++i) {
        float pi = __uint_as_float(__builtin_amdgcn_readlane(__float_as_uint(pold), i));
        q = fmaf(pi, Areg[i], q);
      }
      float lm = __logf(wave_max(pold));
      if (t < sl) {
        pcur = q * __expf(xv - SHIFTC - lm);
        scale += SHIFTC + lm;
      }
    }
    float part = wave_sum(pcur * __expf(lfj));
    if (lane == 0) {
      wsf[WSF_NACC + b]   = part;
      wsf[WSF_NSCALE + b] = scale;
    }
  }
}

__global__ void fsm_final(const float* __restrict__ wsf, float* __restrict__ out) {
  const int tid = threadIdx.x;
  float v = 0.f;
  if (tid < 16)
    v = -(wsf[WSF_NSCALE + tid] + __logf(wsf[WSF_NACC + tid]));
  else if (tid < 32)
    v = (wsf[WSF_DSCALE + tid - 16] + __logf(wsf[WSF_DACC + tid - 16]));
  v = wave_sum(v);
  if (tid == 0) out[0] = v;  // loss = den_sum - num_sum
}

extern "C" void kernel_launch(void* const* d_in, const int* in_sizes, int n_in,
                              void* d_out, int out_size, void* d_ws, size_t ws_size,
                              hipStream_t stream) {
  const float* x    = (const float*)d_in[0];
  const int*   sql  = (const int*)d_in[1];
  const float* nA   = (const float*)d_in[2];
  const float* nls  = (const float*)d_in[3];
  const float* nlf  = (const float*)d_in[4];
  const int*   npdf = (const int*)d_in[5];
  const float* dA   = (const float*)d_in[6];
  const float* dls  = (const float*)d_in[7];
  const float* dlf  = (const float*)d_in[8];
  const int*   dpdf = (const int*)d_in[9];
  float* out = (float*)d_out;
  unsigned long long* p64 = (unsigned long long*)d_ws;
  float* wsf = (float*)d_ws;
  (void)in_sizes; (void)n_in; (void)out_size; (void)ws_size;

  // no memset needed: tags rely on 0xAA poison != any t in [1,500);
  // all accumulators are single-writer and written every launch
  fsm_fwd<<<NDEN + BB, NTHR, 0, stream>>>(x, sql, nA, nls, nlf, npdf,
                                          dA, dls, dlf, dpdf, p64, wsf);
  fsm_final<<<1, 64, 0, stream>>>(wsf, out);
}

// Round 6
// 990.609 us; speedup vs baseline: 1.3614x; 1.3614x over previous
//
#include <hip/hip_runtime.h>
#include <math.h>

#define BB 16
#define TT 500
#define CC 2048
#define SN 64
#define SD 512
#define NDEN 128        // 16 batches * 8 column-blocks
#define NTHR 576        // 8 worker waves + 1 publisher wave
#define SHIFTC 30.0f

// ws layout:
//   bytes [0, 131072): u64 pg[2][16][512] -- (tag<<32)|float_bits
//   float index 32768+: DACC[16], DSCALE[16], NACC[16], NSCALE[16]
#define WSF_DACC   32768
#define WSF_DSCALE 32784
#define WSF_NACC   32800
#define WSF_NSCALE 32816

#define AL(p) __hip_atomic_load((p), __ATOMIC_RELAXED, __HIP_MEMORY_SCOPE_AGENT)
#define AS(p, v) __hip_atomic_store((p), (v), __ATOMIC_RELAXED, __HIP_MEMORY_SCOPE_AGENT)
#define LL(p) __hip_atomic_load((p), __ATOMIC_RELAXED, __HIP_MEMORY_SCOPE_WORKGROUP)
#define LS(p, v) __hip_atomic_store((p), (v), __ATOMIC_RELAXED, __HIP_MEMORY_SCOPE_WORKGROUP)

__device__ __forceinline__ float wave_max(float v) {
  #pragma unroll
  for (int off = 32; off > 0; off >>= 1) v = fmaxf(v, __shfl_xor(v, off, 64));
  return v;
}
__device__ __forceinline__ float wave_sum(float v) {
  #pragma unroll
  for (int off = 32; off > 0; off >>= 1) v += __shfl_xor(v, off, 64);
  return v;
}
__device__ __forceinline__ unsigned long long pk(unsigned tag, float v) {
  return ((unsigned long long)tag << 32) | (unsigned long long)__float_as_uint(v);
}
__device__ __forceinline__ float clamp30(float v) {
  return fminf(fmaxf(v, -30.f), 30.f);
}

__global__ __launch_bounds__(NTHR, 1) void fsm_fwd(
    const float* __restrict__ x, const int* __restrict__ seqlens,
    const float* __restrict__ nA, const float* __restrict__ nls,
    const float* __restrict__ nlf, const int* __restrict__ npdf,
    const float* __restrict__ dA, const float* __restrict__ dls,
    const float* __restrict__ dlf, const int* __restrict__ dpdf,
    unsigned long long* __restrict__ p64, float* __restrict__ wsf)
{
  __shared__ unsigned long long part[2][8][64];  // tagged partial rows
  __shared__ unsigned long long pmax[2][8];      // tagged chunk maxes
  const int tid = threadIdx.x;
  const int lane = tid & 63, wv = tid >> 6;      // wv 0..8

  if (blockIdx.x < NDEN) {
    // ---------------- DEN (shared A, S=512) ---------------------------------
    const int g  = blockIdx.x & 15;     // batch
    const int cb = blockIdx.x >> 4;     // column block (0..7)
    const int j0 = cb * 64;
    unsigned long long* gb0 = p64 + (size_t)g * SD;          // buf 0
    unsigned long long* gb1 = p64 + (size_t)(16 + g) * SD;   // buf 1

    // init LDS tags (sentinel != any t); the ONLY barrier in the den path
    for (int i2 = tid; i2 < 2 * 8 * 64; i2 += NTHR)
      ((unsigned long long*)part)[i2] = 0xFFFFFFFF00000000ull;
    if (tid < 16) ((unsigned long long*)pmax)[tid] = 0xFFFFFFFF00000000ull;
    __syncthreads();

    if (wv < 8) {
      // ---- worker wave: poll remote chunk wv, matvec, push tagged partial ----
      float Areg[64];   // lane holds exp(A[wv*64+k][j0+lane])
      {
        const float* Ap = dA + (size_t)(wv * 64) * SD + j0 + lane;
        #pragma unroll
        for (int k = 0; k < 64; ++k)
          Areg[k] = __expf(Ap[(size_t)k * SD]);
      }
      for (int t = 1; t < TT; ++t) {
        unsigned long long* gin = (t & 1) ? gb0 : gb1;
        const unsigned tg = (unsigned)(t - 1);
        unsigned long long* pa = gin + wv * 64 + lane;
        unsigned long long w;
        for (;;) {
          w = AL(pa);
          if ((unsigned)(w >> 32) == tg) break;
          __builtin_amdgcn_s_sleep(1);
        }
        float pwin = __uint_as_float((unsigned)w);
        float cm = wave_max(pwin);
        float q = 0.f;
        #pragma unroll
        for (int k = 0; k < 64; ++k) {
          float pv = __uint_as_float(__builtin_amdgcn_readlane(__float_as_uint(pwin), k));
          q = fmaf(pv, Areg[k], q);
        }
        LS(&part[t & 1][wv][lane], pk((unsigned)t, q));
        if (lane == 0) LS(&pmax[t & 1][wv], pk((unsigned)t, cm));
        // no barrier — straight to polling t+1
      }
    } else {
      // ---- publisher wave: assemble, renormalize, publish -------------------
      const int   si   = j0 + lane;
      const int   pdfj = dpdf[si];
      const float lfj  = dlf[si];
      const int   sl   = seqlens[g];
      const float* xb  = x + (size_t)g * TT * CC;
      float pcur  = __expf(dls[si] + clamp30(xb[pdfj]) - SHIFTC);
      float scale = SHIFTC;
      AS(gb0 + si, pk(0u, pcur));

      for (int t = 1; t < TT; ++t) {
        float xq = clamp30(xb[(size_t)t * CC + pdfj]);  // in flight during poll
        const unsigned tg = (unsigned)t;
        unsigned long long wr[8], wm[8];
        unsigned miss = 0xFFu;
        do {
          #pragma unroll
          for (int r = 0; r < 8; ++r)
            if (miss & (1u << r)) {
              wr[r] = LL(&part[t & 1][r][lane]);
              wm[r] = LL(&pmax[t & 1][r]);
            }
          #pragma unroll
          for (int r = 0; r < 8; ++r)
            if ((miss & (1u << r)) &&
                (unsigned)(wr[r] >> 32) == tg && (unsigned)(wm[r] >> 32) == tg)
              miss &= ~(1u << r);
        } while (miss);

        float s = 0.f;
        #pragma unroll
        for (int r = 0; r < 8; ++r) s += __uint_as_float((unsigned)wr[r]);
        float m = __uint_as_float((unsigned)wm[0]);
        #pragma unroll
        for (int r = 1; r < 8; ++r) m = fmaxf(m, __uint_as_float((unsigned)wm[r]));
        float lm = __logf(m);
        if (t < sl) {
          pcur = s * __expf(xq - SHIFTC - lm);
          scale += SHIFTC + lm;
        }
        unsigned long long* gout = (t & 1) ? gb1 : gb0;
        AS(gout + si, pk((unsigned)t, pcur));           // coalesced 512B burst
      }
      float prt_ = wave_sum(pcur * __expf(lfj));
      if (lane == 0) {
        atomicAdd(wsf + WSF_DACC + g, prt_);
        if (cb == 0) wsf[WSF_DSCALE + g] = scale;
      }
    }
  } else {
    // ---------------- NUM (per-batch A, S=64), single wave, pure VALU -------
    const int b = blockIdx.x - NDEN;
    if (wv != 0) return;

    float Areg[64];   // lane holds exp(nA[i][lane]) for all i
    {
      const float* Ap = nA + b * SN * SN + lane;
      #pragma unroll
      for (int i = 0; i < 64; ++i)
        Areg[i] = __expf(Ap[i * SN]);
    }
    const int   pdfj = npdf[b * SN + lane];
    const float lfj  = nlf[b * SN + lane];
    const int   sl   = seqlens[b];
    float xv = clamp30(x[(size_t)b * TT * CC + pdfj]);
    float pcur = __expf(nls[b * SN + lane] + xv - SHIFTC);
    float scale = SHIFTC;

    for (int t = 1; t < TT; ++t) {
      xv = clamp30(x[(size_t)b * TT * CC + t * CC + pdfj]);
      float pold = pcur;
      float q = 0.f;
      #pragma unroll
      for (int i = 0; i < 64; ++i) {
        float pi = __uint_as_float(__builtin_amdgcn_readlane(__float_as_uint(pold), i));
        q = fmaf(pi, Areg[i], q);
      }
      float lm = __logf(wave_max(pold));
      if (t < sl) {
        pcur = q * __expf(xv - SHIFTC - lm);
        scale += SHIFTC + lm;
      }
    }
    float part_ = wave_sum(pcur * __expf(lfj));
    if (lane == 0) {
      wsf[WSF_NACC + b]   = part_;
      wsf[WSF_NSCALE + b] = scale;
    }
  }
}

__global__ void fsm_final(const float* __restrict__ wsf, float* __restrict__ out) {
  const int tid = threadIdx.x;
  float v = 0.f;
  if (tid < 16)
    v = -(wsf[WSF_NSCALE + tid] + __logf(wsf[WSF_NACC + tid]));
  else if (tid < 32)
    v = (wsf[WSF_DSCALE + tid - 16] + __logf(wsf[WSF_DACC + tid - 16]));
  v = wave_sum(v);
  if (tid == 0) out[0] = v;  // loss = den_sum - num_sum
}

extern "C" void kernel_launch(void* const* d_in, const int* in_sizes, int n_in,
                              void* d_out, int out_size, void* d_ws, size_t ws_size,
                              hipStream_t stream) {
  const float* x    = (const float*)d_in[0];
  const int*   sql  = (const int*)d_in[1];
  const float* nA   = (const float*)d_in[2];
  const float* nls  = (const float*)d_in[3];
  const float* nlf  = (const float*)d_in[4];
  const int*   npdf = (const int*)d_in[5];
  const float* dA   = (const float*)d_in[6];
  const float* dls  = (const float*)d_in[7];
  const float* dlf  = (const float*)d_in[8];
  const int*   dpdf = (const int*)d_in[9];
  float* out = (float*)d_out;
  unsigned long long* p64 = (unsigned long long*)d_ws;
  float* wsf = (float*)d_ws;
  (void)in_sizes; (void)n_in; (void)out_size; (void)ws_size;

  // zero the DACC accumulators (atomicAdd targets); tagged region relies on
  // 0xAA poison != any tag in [0,500)
  hipMemsetAsync((char*)d_ws + 131072, 0, 256, stream);
  fsm_fwd<<<NDEN + BB, NTHR, 0, stream>>>(x, sql, nA, nls, nlf, npdf,
                                          dA, dls, dlf, dpdf, p64, wsf);
  fsm_final<<<1, 64, 0, stream>>>(wsf, out);
}

// Round 7
// 932.924 us; speedup vs baseline: 1.4456x; 1.0618x over previous
//
#include <hip/hip_runtime.h>
#include <math.h>

#define BB 16
#define TT 500
#define CC 2048
#define SN 64
#define SD 512
#define NDEN 128        // 16 batches * 8 column-blocks
#define NTHR 512
#define SHIFTC 30.0f

// ws layout:
//   bytes [0, 131072): u64 pg[2][16][512] -- (tag<<32)|float_bits
//   float index 32768+: DACC[16], DSCALE[16], NACC[16], NSCALE[16]
#define WSF_DACC   32768
#define WSF_DSCALE 32784
#define WSF_NACC   32800
#define WSF_NSCALE 32816

#define AL(p) __hip_atomic_load((p), __ATOMIC_RELAXED, __HIP_MEMORY_SCOPE_AGENT)
#define AS(p, v) __hip_atomic_store((p), (v), __ATOMIC_RELAXED, __HIP_MEMORY_SCOPE_AGENT)

__device__ __forceinline__ float wave_max(float v) {
  #pragma unroll
  for (int off = 32; off > 0; off >>= 1) v = fmaxf(v, __shfl_xor(v, off, 64));
  return v;
}
__device__ __forceinline__ float wave_sum(float v) {
  #pragma unroll
  for (int off = 32; off > 0; off >>= 1) v += __shfl_xor(v, off, 64);
  return v;
}
__device__ __forceinline__ unsigned long long pk(unsigned tag, float v) {
  return ((unsigned long long)tag << 32) | (unsigned long long)__float_as_uint(v);
}
__device__ __forceinline__ float clamp30(float v) {
  return fminf(fmaxf(v, -30.f), 30.f);
}

__global__ __launch_bounds__(NTHR, 1) void fsm_fwd(
    const float* __restrict__ x, const int* __restrict__ seqlens,
    const float* __restrict__ nA, const float* __restrict__ nls,
    const float* __restrict__ nlf, const int* __restrict__ npdf,
    const float* __restrict__ dA, const float* __restrict__ dls,
    const float* __restrict__ dlf, const int* __restrict__ dpdf,
    unsigned long long* __restrict__ p64, float* __restrict__ wsf)
{
  __shared__ float prt[2][8][64];   // double-buffered per-wave partial q
  __shared__ float pmx[2][8];       // double-buffered per-wave chunk maxes
  const int tid = threadIdx.x;
  const int lane = tid & 63, wv = tid >> 6;

  if (blockIdx.x < NDEN) {
    // ---------------- DEN (shared A, S=512), 1 batch per group --------------
    const int g  = blockIdx.x & 15;     // batch
    const int cb = blockIdx.x >> 4;     // column block (0..7)
    const int j0 = cb * 64;

    // A in registers: lane holds exp(A[wv*64+k][j0+lane]), k=0..63
    float Areg[64];
    {
      const float* Ap = dA + (size_t)(wv * 64) * SD + j0 + lane;
      #pragma unroll
      for (int k = 0; k < 64; ++k)
        Areg[k] = __expf(Ap[(size_t)k * SD]);
    }

    unsigned long long* gb0 = p64 + (size_t)g * SD;          // buf 0
    unsigned long long* gb1 = p64 + (size_t)(16 + g) * SD;   // buf 1

    // wave 0 owns the epilogue for this WG's 64 columns
    const int si = j0 + lane;
    int pdfj = 0, sl = 0; float lfj = 0.f, pcur = 0.f, scale = SHIFTC;
    const float* xb = x + (size_t)g * TT * CC;
    if (wv == 0) {
      pdfj = dpdf[si];
      lfj  = dlf[si];
      sl   = seqlens[g];
      float xv = clamp30(xb[pdfj]);
      pcur = __expf(dls[si] + xv - SHIFTC);
      AS(gb0 + si, pk(0u, pcur));
    }
    float lmlag = 0.f;   // lm(p_{t-2}) entering step t; 0 for t=1

    for (int t = 1; t < TT; ++t) {
      unsigned long long* gin  = (t & 1) ? gb0 : gb1;
      unsigned long long* gout = (t & 1) ? gb1 : gb0;

      // wave0: precompute the full emission*renorm factor BEFORE the barrier
      // (uses lag-2 lm -> no dependence on this step's max)
      float emfac = 0.f;
      if (wv == 0) {
        float xq = clamp30(xb[(size_t)t * CC + pdfj]);
        emfac = __expf(xq - SHIFTC - lmlag);
      }

      // pipelined 2-deep poll of own remote chunk (1 tagged u64 per lane)
      const unsigned tg = (unsigned)(t - 1);
      unsigned long long* pa = gin + wv * 64 + lane;
      float pwin;
      {
        unsigned long long w = AL(pa);
        for (;;) {
          unsigned long long wn = AL(pa);        // keep one load in flight
          if ((unsigned)(w >> 32) == tg) {       // check the OLDER load (vmcnt(1))
            pwin = __uint_as_float((unsigned)w);
            break;
          }
          __builtin_amdgcn_s_sleep(1);
          w = wn;
        }
      }

      // matvec over own i-window (pure VALU, readlane broadcast)
      float q = 0.f;
      #pragma unroll
      for (int k = 0; k < 64; ++k) {
        float pv = __uint_as_float(__builtin_amdgcn_readlane(__float_as_uint(pwin), k));
        q = fmaf(pv, Areg[k], q);
      }
      prt[t & 1][wv][lane] = q;
      float cm = wave_max(pwin);                 // max of consumed chunk (for lm)
      if (lane == 0) pmx[t & 1][wv] = cm;
      __syncthreads();   // the one per-step barrier

      if (wv == 0) {
        float s = 0.f;
        #pragma unroll
        for (int r = 0; r < 8; ++r) s += prt[t & 1][r][lane];
        if (t < sl) {
          pcur = s * emfac;
          scale += SHIFTC + lmlag;
        }
        AS(gout + si, pk((unsigned)t, pcur));    // publish ASAP (coalesced 512B)
        // post-store: compute lm(p_{t-1}) for step t+1 (off the critical path)
        float m = pmx[t & 1][0];
        #pragma unroll
        for (int r = 1; r < 8; ++r) m = fmaxf(m, pmx[t & 1][r]);
        lmlag = __logf(m);
      }
      // waves 1..7 go straight to polling t+1 (prt/pmx double-buffered)
    }
    if (wv == 0) {
      float part = wave_sum(pcur * __expf(lfj));
      if (lane == 0) {
        atomicAdd(wsf + WSF_DACC + g, part);
        if (cb == 0) wsf[WSF_DSCALE + g] = scale;
      }
    }
  } else {
    // ---------------- NUM (per-batch A, S=64), single wave, pure VALU -------
    const int b = blockIdx.x - NDEN;
    if (wv != 0) return;

    float Areg[64];   // lane holds exp(nA[i][lane]) for all i
    {
      const float* Ap = nA + b * SN * SN + lane;
      #pragma unroll
      for (int i = 0; i < 64; ++i)
        Areg[i] = __expf(Ap[i * SN]);
    }
    const int   pdfj = npdf[b * SN + lane];
    const float lfj  = nlf[b * SN + lane];
    const int   sl   = seqlens[b];
    float xv = clamp30(x[(size_t)b * TT * CC + pdfj]);
    float pcur = __expf(nls[b * SN + lane] + xv - SHIFTC);
    float scale = SHIFTC;

    for (int t = 1; t < TT; ++t) {
      xv = clamp30(x[(size_t)b * TT * CC + t * CC + pdfj]);
      float pold = pcur;
      float q = 0.f;
      #pragma unroll
      for (int i = 0; i < 64; ++i) {
        float pi = __uint_as_float(__builtin_amdgcn_readlane(__float_as_uint(pold), i));
        q = fmaf(pi, Areg[i], q);
      }
      float lm = __logf(wave_max(pold));
      if (t < sl) {
        pcur = q * __expf(xv - SHIFTC - lm);
        scale += SHIFTC + lm;
      }
    }
    float part = wave_sum(pcur * __expf(lfj));
    if (lane == 0) {
      wsf[WSF_NACC + b]   = part;
      wsf[WSF_NSCALE + b] = scale;
    }
  }
}

__global__ void fsm_final(const float* __restrict__ wsf, float* __restrict__ out) {
  const int tid = threadIdx.x;
  float v = 0.f;
  if (tid < 16)
    v = -(wsf[WSF_NSCALE + tid] + __logf(wsf[WSF_NACC + tid]));
  else if (tid < 32)
    v = (wsf[WSF_DSCALE + tid - 16] + __logf(wsf[WSF_DACC + tid - 16]));
  v = wave_sum(v);
  if (tid == 0) out[0] = v;  // loss = den_sum - num_sum
}

extern "C" void kernel_launch(void* const* d_in, const int* in_sizes, int n_in,
                              void* d_out, int out_size, void* d_ws, size_t ws_size,
                              hipStream_t stream) {
  const float* x    = (const float*)d_in[0];
  const int*   sql  = (const int*)d_in[1];
  const float* nA   = (const float*)d_in[2];
  const float* nls  = (const float*)d_in[3];
  const float* nlf  = (const float*)d_in[4];
  const int*   npdf = (const int*)d_in[5];
  const float* dA   = (const float*)d_in[6];
  const float* dls  = (const float*)d_in[7];
  const float* dlf  = (const float*)d_in[8];
  const int*   dpdf = (const int*)d_in[9];
  float* out = (float*)d_out;
  unsigned long long* p64 = (unsigned long long*)d_ws;
  float* wsf = (float*)d_ws;
  (void)in_sizes; (void)n_in; (void)out_size; (void)ws_size;

  // zero the DACC accumulators (atomicAdd targets); tagged region relies on
  // 0xAA poison != any tag in [0,500)
  hipMemsetAsync((char*)d_ws + 131072, 0, 256, stream);
  fsm_fwd<<<NDEN + BB, NTHR, 0, stream>>>(x, sql, nA, nls, nlf, npdf,
                                          dA, dls, dlf, dpdf, p64, wsf);
  fsm_final<<<1, 64, 0, stream>>>(wsf, out);
}